// Round 6
// baseline (80.360 us; speedup 1.0000x reference)
//
#include <hip/hip_runtime.h>
#include <math.h>

#define NQ    12
#define NST   4096
#define NL    4
#define NBATCH 2048
#define DIM   64
#define NCLS  4
#define TPB   512
#define APT   8       // amps per thread

typedef float v2f __attribute__((ext_vector_type(2)));   // (re, im)

// CNOT ring composition (verified round 1): new[d] = old[cnot_perm(d)]. XOR-linear.
constexpr unsigned cnot_perm(unsigned i) {
    unsigned s = i ^ ((i & 1u) << 11);
    for (int pc = 1; pc <= 11; ++pc)
        s ^= ((s >> pc) & 1u) << (pc - 1);
    return s;
}

// LDS swizzle on f2 index: XOR bits 9:5 into bank bits 4:0 (verified round 5).
constexpr unsigned swz(unsigned j) { return j ^ ((j >> 5) & 31u); }

// B-layout k constants: i_B k bits -> global bits 9,10,11 -> swz adds (k&1)<<4
constexpr unsigned kBC(int k) { return ((unsigned)k << 9) ^ (((unsigned)k & 1u) << 4); }
// ring-gather constants: swz(P(k)), P(k) bits within {0,1,2,10,11} (swz-invariant)
constexpr unsigned kCK(int k) { return swz(cnot_perm((unsigned)k)); }

// lane exchange via DPP only: XB in {1,2,8}
template<int XB>
__device__ __forceinline__ float lx(float v) {
    int i = __float_as_int(v);
    if constexpr (XB == 1) {
        return __int_as_float(__builtin_amdgcn_update_dpp(i, i, 0xB1, 0xF, 0xF, true));  // quad_perm [1,0,3,2]
    } else if constexpr (XB == 2) {
        return __int_as_float(__builtin_amdgcn_update_dpp(i, i, 0x4E, 0xF, 0xF, true));  // quad_perm [2,3,0,1]
    } else {
        return __int_as_float(__builtin_amdgcn_update_dpp(i, i, 0x128, 0xF, 0xF, true)); // row_ror:8 == lane^8
    }
}

// gate on intra-register bit P (0..2). PH=false: RZ dropped (layer 3).
template<int P, bool PH>
__device__ __forceinline__ void intra_g(v2f (&a)[APT], float c, float s, float pc, float ps) {
    #pragma unroll
    for (int k = 0; k < APT; ++k) {
        if (!(k & (1 << P))) {
            const int k1 = k | (1 << P);
            v2f x0 = a[k], x1 = a[k1];
            v2f t0 = c*x0 - s*x1;          // packed over (re,im)
            v2f t1 = s*x0 + c*x1;
            a[k] = t0;
            if constexpr (PH) {
                a[k1].x = pc*t1.x - ps*t1.y;
                a[k1].y = pc*t1.y + ps*t1.x;
            } else {
                a[k1] = t1;
            }
        }
    }
}

// gate on lane bit XB (DPP). out = A*mine + B*other, A,B hoisted per lane.
template<int XB, bool PH>
__device__ __forceinline__ void lane_g(v2f (&a)[APT], float c, float s, float pc, float ps, int lane) {
    const bool b = (lane & XB) != 0;
    if constexpr (PH) {
        const float Ar = b ? c*pc : c;
        const float Ai = b ? c*ps : 0.f;
        const float Br = b ? s*pc : -s;
        const float Bi = b ? s*ps : 0.f;
        #pragma unroll
        for (int k = 0; k < APT; ++k) {
            v2f o; o.x = lx<XB>(a[k].x); o.y = lx<XB>(a[k].y);
            v2f m = a[k];
            v2f t = Ar*m + Br*o;           // packed (real-coef part)
            a[k].x = t.x - Ai*m.y - Bi*o.y;
            a[k].y = t.y + Ai*m.x + Bi*o.x;
        }
    } else {
        const float Br = b ? s : -s;
        #pragma unroll
        for (int k = 0; k < APT; ++k) {
            v2f o; o.x = lx<XB>(a[k].x); o.y = lx<XB>(a[k].y);
            a[k] = c*a[k] + Br*o;          // 2 packed insts
        }
    }
}

__device__ __forceinline__ void a_write(const v2f (&a)[APT], v2f* buf, unsigned Abase, int a0) {
    float4* f4 = (float4*)buf;
    #pragma unroll
    for (int ke = 0; ke < APT; ke += 2) {
        v2f lo = a0 ? a[ke+1] : a[ke];
        v2f hi = a0 ? a[ke]   : a[ke+1];
        f4[(Abase ^ (unsigned)ke) >> 1] = make_float4(lo.x, lo.y, hi.x, hi.y);
    }
}

__device__ __forceinline__ void ring_gather(v2f (&a)[APT], const v2f* buf, unsigned rbase) {
    #pragma unroll
    for (int k = 0; k < APT; ++k)
        a[k] = buf[rbase ^ kCK(k)];
}

// One layer: A-phase gates -> relayout -> B-phase gates -> write -> ring gather.
// A: intra q11,q10,q9 ; DPP l0->q8, l1->q7, l3->q5.
// B: intra q2,q1,q0 (k->bits 9,10,11) ; DPP l0->q6, l1->q4, l3->q3.
template<bool PH>
__device__ __forceinline__ void apply_layer(v2f (&a)[APT], v2f* buf, const float* __restrict__ P,
    unsigned Abase, unsigned Bbase, unsigned rbase, int lane, int a0) {
    intra_g<0,PH>(a, P[11*4+0], P[11*4+1], P[11*4+2], P[11*4+3]);
    intra_g<1,PH>(a, P[10*4+0], P[10*4+1], P[10*4+2], P[10*4+3]);
    intra_g<2,PH>(a, P[ 9*4+0], P[ 9*4+1], P[ 9*4+2], P[ 9*4+3]);
    lane_g<1,PH>(a, P[ 8*4+0], P[ 8*4+1], P[ 8*4+2], P[ 8*4+3], lane);
    lane_g<2,PH>(a, P[ 7*4+0], P[ 7*4+1], P[ 7*4+2], P[ 7*4+3], lane);
    lane_g<8,PH>(a, P[ 5*4+0], P[ 5*4+1], P[ 5*4+2], P[ 5*4+3], lane);
    a_write(a, buf, Abase, a0);
    __syncthreads();
    #pragma unroll
    for (int k = 0; k < APT; ++k)
        a[k] = buf[Bbase ^ kBC(k)];
    intra_g<0,PH>(a, P[ 2*4+0], P[ 2*4+1], P[ 2*4+2], P[ 2*4+3]);
    intra_g<1,PH>(a, P[ 1*4+0], P[ 1*4+1], P[ 1*4+2], P[ 1*4+3]);
    intra_g<2,PH>(a, P[ 0*4+0], P[ 0*4+1], P[ 0*4+2], P[ 0*4+3]);
    lane_g<1,PH>(a, P[ 6*4+0], P[ 6*4+1], P[ 6*4+2], P[ 6*4+3], lane);
    lane_g<2,PH>(a, P[ 4*4+0], P[ 4*4+1], P[ 4*4+2], P[ 4*4+3], lane);
    lane_g<8,PH>(a, P[ 3*4+0], P[ 3*4+1], P[ 3*4+2], P[ 3*4+3], lane);
    // write back own amps (same addrs read above: same-thread, no barrier needed)
    #pragma unroll
    for (int k = 0; k < APT; ++k)
        buf[Bbase ^ kBC(k)] = a[k];
    __syncthreads();
    ring_gather(a, buf, rbase);
    __syncthreads();
}

// 1-block setup: layers 1..3 shared-gate params -> d_ws (main kernel reads
// them via uniform loads, keeping the per-gate coefficients off the LDS pipe)
__global__ void vqc_setup(const float* __restrict__ qw, float* __restrict__ gp) {
    int t = threadIdx.x;
    if (t < 36) {
        int l = 1 + t / 12, q = t % 12;
        float th = qw[(l*NQ + q)*2 + 0];
        float ph = qw[(l*NQ + q)*2 + 1];
        float cc, ss; sincosf(0.5f*th, &ss, &cc);
        float pcv, psv; sincosf(ph, &psv, &pcv);
        gp[(l-1)*48 + q*4 + 0] = cc;
        gp[(l-1)*48 + q*4 + 1] = ss;
        gp[(l-1)*48 + q*4 + 2] = pcv;
        gp[(l-1)*48 + q*4 + 3] = psv;
    }
}

__global__ __launch_bounds__(TPB, 2) void vqc_kernel(
    const float* __restrict__ x,
    const float* __restrict__ Win,
    const float* __restrict__ bin,
    const float* __restrict__ qw,
    const float* __restrict__ Wout,
    const float* __restrict__ bout,
    const float* __restrict__ gp,   // [3][12][4] from setup kernel
    float* __restrict__ out)
{
    __shared__ __align__(16) v2f buf[NST];   // 32 KB
    __shared__ float xs[DIM];
    __shared__ float g0[4*NQ];               // layer-0 per-sample params [q*4+{c,s,pc,ps}]
    __shared__ float zred[8*10];
    __shared__ float zfin[NQ];

    const int tid  = threadIdx.x;
    const int lane = tid & 63;
    const int wv   = tid >> 6;
    const int b    = blockIdx.x;

    const unsigned Abase = swz((unsigned)tid << 3);
    // layout B: k->bits 9,10,11 ; l0->5, l1->7, l2->3, l3->8, l4->4, l5->6 ; wv->0,1,2
    const unsigned iB0 = ((unsigned)(lane & 1)  << 5) | ((unsigned)(lane & 2)  << 6) |
                         ((unsigned)(lane & 4)  << 1) | ((unsigned)(lane & 8)  << 5) |
                         ((unsigned)(lane & 16))      | ((unsigned)(lane & 32) << 1) |
                         (unsigned)wv;
    const unsigned Bbase = swz(iB0);
    const unsigned rbase = swz(cnot_perm((unsigned)tid << 3));
    const int a0 = (int)(Abase & 1u);

    // ---- stage x ----
    if (tid < DIM) xs[tid] = x[b*DIM + tid];
    __syncthreads();

    // ---- encoding matvec (16 lanes/qubit), folded into layer-0 RY ----
    if (tid < 192) {
        const int q = tid >> 4, r = tid & 15;
        float acc = xs[r] * Win[q*DIM + r]
                  + xs[r+16] * Win[q*DIM + r + 16]
                  + xs[r+32] * Win[q*DIM + r + 32]
                  + xs[r+48] * Win[q*DIM + r + 48];
        acc += __shfl_xor(acc, 8, 16);
        acc += __shfl_xor(acc, 4, 16);
        acc += __shfl_xor(acc, 2, 16);
        acc += __shfl_xor(acc, 1, 16);
        if (r == 0) {
            acc += bin[q];
            float ang = tanhf(acc) * 3.14159265358979323846f;
            float th  = ang + qw[(0*NQ + q)*2 + 0];
            float ph  = qw[(0*NQ + q)*2 + 1];
            float cc, ss; sincosf(0.5f*th, &ss, &cc);
            float pcv, psv; sincosf(ph, &psv, &pcv);
            g0[q*4+0] = cc; g0[q*4+1] = ss; g0[q*4+2] = pcv; g0[q*4+3] = psv;
        }
    }
    __syncthreads();

    v2f a[APT];

    // ---- layer 0 on |0..0>: product state in layout A ----
    {
        v2f tf = (v2f){1.f, 0.f};
        #pragma unroll
        for (int p = 3; p <= 11; ++p) {
            const int q = 11 - p;
            const int bit = (tid >> (p - 3)) & 1;
            float fr = bit ? g0[q*4+1]*g0[q*4+2] : g0[q*4+0];
            float fi = bit ? g0[q*4+1]*g0[q*4+3] : 0.f;
            v2f nt;
            nt.x = tf.x*fr - tf.y*fi;
            nt.y = tf.x*fi + tf.y*fr;
            tf = nt;
        }
        float f0r[2], f0i[2], f1r[2], f1i[2], f2r[2], f2i[2];
        f0r[0] = g0[11*4+0]; f0i[0] = 0.f; f0r[1] = g0[11*4+1]*g0[11*4+2]; f0i[1] = g0[11*4+1]*g0[11*4+3];
        f1r[0] = g0[10*4+0]; f1i[0] = 0.f; f1r[1] = g0[10*4+1]*g0[10*4+2]; f1i[1] = g0[10*4+1]*g0[10*4+3];
        f2r[0] = g0[ 9*4+0]; f2i[0] = 0.f; f2r[1] = g0[ 9*4+1]*g0[ 9*4+2]; f2i[1] = g0[ 9*4+1]*g0[ 9*4+3];
        float hr[4], hi[4];
        #pragma unroll
        for (int j = 0; j < 4; ++j) {
            const int b0 = j & 1, b1 = (j >> 1) & 1;
            hr[j] = f0r[b0]*f1r[b1] - f0i[b0]*f1i[b1];
            hi[j] = f0r[b0]*f1i[b1] + f0i[b0]*f1r[b1];
        }
        #pragma unroll
        for (int k = 0; k < APT; ++k) {
            const int j = k & 3, b2 = k >> 2;
            float gr = hr[j]*f2r[b2] - hi[j]*f2i[b2];
            float gi = hr[j]*f2i[b2] + hi[j]*f2r[b2];
            a[k].x = tf.x*gr - tf.y*gi;
            a[k].y = tf.x*gi + tf.y*gr;
        }
    }

    // ---- layer-0 ring ----
    a_write(a, buf, Abase, a0);
    __syncthreads();
    ring_gather(a, buf, rbase);
    __syncthreads();

    // ---- layers 1..3 (layer 3 without RZ: diagonal phase invisible to |amp|^2) ----
    apply_layer<true >(a, buf, gp +  0, Abase, Bbase, rbase, lane, a0);
    apply_layer<true >(a, buf, gp + 48, Abase, Bbase, rbase, lane, a0);
    apply_layer<false>(a, buf, gp + 96, Abase, Bbase, rbase, lane, a0);

    // ---- measurement (layout A: i = tid*8+k) ----
    float psum = 0.f, zk0 = 0.f, zk1 = 0.f, zk2 = 0.f;
    #pragma unroll
    for (int k = 0; k < APT; ++k) {
        float p = a[k].x*a[k].x + a[k].y*a[k].y;
        psum += p;
        zk0 += (k & 1) ? -p : p;     // qubit 11
        zk1 += (k & 2) ? -p : p;     // qubit 10
        zk2 += (k & 4) ? -p : p;     // qubit 9
    }
    #pragma unroll
    for (int off = 1; off < 64; off <<= 1) {
        zk0 += __shfl_xor(zk0, off, 64);
        zk1 += __shfl_xor(zk1, off, 64);
        zk2 += __shfl_xor(zk2, off, 64);
    }
    // WHT butterfly: lanes {0,1,2,4,8,16,32} = total + 6 single-lane-bit signed sums
    float w = psum;
    #pragma unroll
    for (int t = 0; t < 6; ++t) {
        float o = __shfl_xor(w, 1 << t, 64);
        w = ((lane >> t) & 1) ? (o - w) : (w + o);
    }
    if (lane == 0) {
        zred[wv*10 + 0] = zk0;
        zred[wv*10 + 1] = zk1;
        zred[wv*10 + 2] = zk2;
        zred[wv*10 + 3] = w;          // psum total
    } else if ((lane & (lane - 1)) == 0) {
        int j = __ffs(lane) - 1;      // lane bit j -> qubit 8-j
        zred[wv*10 + 4 + j] = w;
    }
    __syncthreads();
    if (tid < NQ) {
        const int q = tid;
        float acc = 0.f;
        if (q >= 9) {
            const int s_ = 11 - q;
            #pragma unroll
            for (int v2 = 0; v2 < 8; ++v2) acc += zred[v2*10 + s_];
        } else if (q >= 3) {
            const int s_ = 4 + (8 - q);
            #pragma unroll
            for (int v2 = 0; v2 < 8; ++v2) acc += zred[v2*10 + s_];
        } else {
            const int bp = 2 - q;     // qubit 2,1,0 <-> wv bit 0,1,2
            #pragma unroll
            for (int v2 = 0; v2 < 8; ++v2)
                acc += ((v2 >> bp) & 1) ? -zred[v2*10 + 3] : zred[v2*10 + 3];
        }
        zfin[q] = acc;
    }
    __syncthreads();

    // ---- classifier head ----
    if (tid < NCLS) {
        float acc = bout[tid];
        #pragma unroll
        for (int q = 0; q < NQ; ++q) acc += zfin[q] * Wout[tid*NQ + q];
        out[b*NCLS + tid] = acc;
    }
}

extern "C" void kernel_launch(void* const* d_in, const int* in_sizes, int n_in,
                              void* d_out, int out_size, void* d_ws, size_t ws_size,
                              hipStream_t stream) {
    const float* x    = (const float*)d_in[0];
    const float* Win  = (const float*)d_in[1];
    const float* bin  = (const float*)d_in[2];
    const float* qw   = (const float*)d_in[3];
    const float* Wout = (const float*)d_in[4];
    const float* bout = (const float*)d_in[5];
    float* gp  = (float*)d_ws;       // 144 floats
    float* out = (float*)d_out;
    hipLaunchKernelGGL(vqc_setup, dim3(1), dim3(64), 0, stream, qw, gp);
    hipLaunchKernelGGL(vqc_kernel, dim3(NBATCH), dim3(TPB), 0, stream,
                       x, Win, bin, qw, Wout, bout, gp, out);
}

// Round 7
// 53.374 us; speedup vs baseline: 1.5056x; 1.5056x over previous
//
#include <hip/hip_runtime.h>
#include <math.h>

#define NQ    12
#define NST   4096
#define NL    4
#define NBATCH 2048
#define DIM   64
#define NCLS  4
#define TPB   512
#define APT   8

typedef float v2f __attribute__((ext_vector_type(2)));   // (re, im)

// Ring permutation (round-1 verified cnot_perm), closed linear form:
// P(j) = j ^ (j>>1) ^ (j0 ? e10^e11 : 0).  new_state[d] = old[P(d)].
constexpr unsigned Pm(unsigned j) { return j ^ (j >> 1) ^ ((j & 1u) * 0xC00u); }

// Storage map L: addr0=j0^j3, addr1=j1^j4, addr2=j2^j5, addr3=j3^j6,
// addr4=j4^j8, bits 5..11 identity. Bijective; chosen so that all six access
// patterns (A/B phases of layers 1..3 with maps L, L∘P, L∘P^2) are
// bank-conflict-free (rank-5 low-address forms over lane bits).
constexpr unsigned Lm(unsigned j) {
    return (j & ~0x1Fu) | ((j ^ (j >> 3)) & 0xFu) | ((((j >> 4) ^ (j >> 8)) & 1u) << 4);
}

// B-layout: logical bit <- {b0=l4, b1=wv0, b2=wv1, b3=wv2, b4=l2, b5=l0,
// b6=l5, b7=l1, b8=l3}, k slots at bits 9,10,11 (qubits 2,1,0).
__device__ __forceinline__ unsigned beta_of(int lane, int wv) {
    return ((unsigned)(lane >> 4) & 1u)       | (((unsigned)wv & 1u) << 1)
         | (((unsigned)(wv >> 1) & 1u) << 2)  | (((unsigned)(wv >> 2) & 1u) << 3)
         | (((unsigned)(lane >> 2) & 1u) << 4)| (((unsigned)lane & 1u) << 5)
         | (((unsigned)(lane >> 5) & 1u) << 6)| (((unsigned)(lane >> 1) & 1u) << 7)
         | (((unsigned)(lane >> 3) & 1u) << 8);
}

__device__ __forceinline__ v2f cmul(v2f x, v2f y) {
    v2f r; r.x = x.x*y.x - x.y*y.y; r.y = x.x*y.y + x.y*y.x; return r;
}

// lane exchange, DPP-only (XB in {1,2,8})
template<int XB>
__device__ __forceinline__ float lx(float v) {
    int i = __float_as_int(v);
    if constexpr (XB == 1) {
        return __int_as_float(__builtin_amdgcn_update_dpp(i, i, 0xB1, 0xF, 0xF, true));  // quad_perm [1,0,3,2]
    } else if constexpr (XB == 2) {
        return __int_as_float(__builtin_amdgcn_update_dpp(i, i, 0x4E, 0xF, 0xF, true));  // quad_perm [2,3,0,1]
    } else {
        return __int_as_float(__builtin_amdgcn_update_dpp(i, i, 0x128, 0xF, 0xF, true)); // row_ror:8 == lane^8
    }
}

// real RY on intra-register bit P
template<int P>
__device__ __forceinline__ void intra_g(v2f (&a)[APT], float c, float s) {
    #pragma unroll
    for (int k = 0; k < APT; ++k) {
        if (!(k & (1 << P))) {
            const int k1 = k | (1 << P);
            v2f x0 = a[k], x1 = a[k1];
            a[k]  = c*x0 - s*x1;
            a[k1] = s*x0 + c*x1;
        }
    }
}

// real RY on lane bit XB
template<int XB>
__device__ __forceinline__ void lane_g(v2f (&a)[APT], float c, float s, int lane) {
    const float Br = (lane & XB) ? s : -s;
    #pragma unroll
    for (int k = 0; k < APT; ++k) {
        v2f o; o.x = lx<XB>(a[k].x); o.y = lx<XB>(a[k].y);
        a[k] = c*a[k] + Br*o;
    }
}

// A-phase gates: intra bits 0,1,2 = qubits 11,10,9 ; lanes l0,l1,l3 at logical
// bits 3,4,6 = qubits 8,7,5
__device__ __forceinline__ void gates_A(v2f (&a)[APT], const float* __restrict__ cs, int lane) {
    intra_g<0>(a, cs[11*2], cs[11*2+1]);
    intra_g<1>(a, cs[10*2], cs[10*2+1]);
    intra_g<2>(a, cs[ 9*2], cs[ 9*2+1]);
    lane_g<1>(a, cs[8*2], cs[8*2+1], lane);
    lane_g<2>(a, cs[7*2], cs[7*2+1], lane);
    lane_g<8>(a, cs[5*2], cs[5*2+1], lane);
}
// B-phase gates: intra bits (logical 9,10,11) = qubits 2,1,0 ; lanes l0,l1,l3
// at logical bits 5,7,8 = qubits 6,4,3
__device__ __forceinline__ void gates_B(v2f (&a)[APT], const float* __restrict__ cs, int lane) {
    intra_g<0>(a, cs[2*2], cs[2*2+1]);
    intra_g<1>(a, cs[1*2], cs[1*2+1]);
    intra_g<2>(a, cs[0*2], cs[0*2+1]);
    lane_g<1>(a, cs[6*2], cs[6*2+1], lane);
    lane_g<2>(a, cs[4*2], cs[4*2+1], lane);
    lane_g<8>(a, cs[3*2], cs[3*2+1], lane);
}

// ws layout (floats): [0..71] RY c/s layers1-3; [72..103] kD layers1-2;
// [104..1127] thrD layer1 (512 v2f); [1128..2151] thrD layer2
__global__ void vqc_setup(const float* __restrict__ qw, float* __restrict__ gp) {
    const int t = threadIdx.x;
    const int lane = t & 63, wv = t >> 6;
    if (t < 36) {
        int l = t / 12 + 1, q = t % 12;
        float th = qw[(l*NQ + q)*2];
        float cc, ss; sincosf(0.5f*th, &ss, &cc);
        gp[((l-1)*NQ + q)*2 + 0] = cc;
        gp[((l-1)*NQ + q)*2 + 1] = ss;
    }
    if (t >= 64 && t < 80) {
        int i = t - 64, l = i/8 + 1, k = i%8;
        float ang = 0.f;
        if (k & 1) ang += qw[(l*NQ + 2)*2 + 1];
        if (k & 2) ang += qw[(l*NQ + 1)*2 + 1];
        if (k & 4) ang += qw[(l*NQ + 0)*2 + 1];
        float s_, c_; sincosf(ang, &s_, &c_);
        gp[72 + (l-1)*16 + k*2 + 0] = c_;
        gp[72 + (l-1)*16 + k*2 + 1] = s_;
    }
    const unsigned be = beta_of(lane, wv);
    #pragma unroll
    for (int l = 1; l <= 2; ++l) {
        float ang = 0.f;
        #pragma unroll
        for (int b = 0; b <= 8; ++b)
            if ((be >> b) & 1) ang += qw[(l*NQ + (11 - b))*2 + 1];
        float s_, c_; sincosf(ang, &s_, &c_);
        gp[104 + (l-1)*1024 + t*2 + 0] = c_;
        gp[104 + (l-1)*1024 + t*2 + 1] = s_;
    }
}

__global__ __launch_bounds__(TPB, 4) void vqc_kernel(
    const float* __restrict__ x,
    const float* __restrict__ Win,
    const float* __restrict__ bin,
    const float* __restrict__ qw,
    const float* __restrict__ Wout,
    const float* __restrict__ bout,
    const float* __restrict__ gp,
    float* __restrict__ out)
{
    __shared__ __align__(16) v2f buf[NST];   // 32 KB
    __shared__ float xs[DIM];
    __shared__ float g0c[NQ], g0r[NQ], g0i[NQ];  // layer-0 factors f(0)=(c,0), f(1)=(r,i)
    __shared__ float zred[8][9];
    __shared__ float zfin[NQ];

    const int tid  = threadIdx.x;
    const int lane = tid & 63;
    const int wv   = tid >> 6;
    const int b    = blockIdx.x;

    const unsigned al  = (unsigned)tid << 3;
    const unsigned be  = beta_of(lane, wv);
    const unsigned LA1 = Lm(al),      LB1 = Lm(be);
    const unsigned LA2 = Lm(Pm(al)),  LB2 = Lm(Pm(be));
    const unsigned LA3 = Lm(Pm(Pm(al))), LB3 = Lm(Pm(Pm(be)));

    // ---- stage x ----
    if (tid < DIM) xs[tid] = x[b*DIM + tid];
    __syncthreads();

    // ---- encoding matvec (16 lanes/qubit); layer-0 factors with RZ folded ----
    if (tid < 192) {
        const int q = tid >> 4, r = tid & 15;
        float acc = xs[r] * Win[q*DIM + r]
                  + xs[r+16] * Win[q*DIM + r + 16]
                  + xs[r+32] * Win[q*DIM + r + 32]
                  + xs[r+48] * Win[q*DIM + r + 48];
        acc += __shfl_xor(acc, 8, 16);
        acc += __shfl_xor(acc, 4, 16);
        acc += __shfl_xor(acc, 2, 16);
        acc += __shfl_xor(acc, 1, 16);
        if (r == 0) {
            acc += bin[q];
            float ang = tanhf(acc) * 3.14159265358979323846f;
            float th  = ang + qw[(0*NQ + q)*2 + 0];
            float ph  = qw[(0*NQ + q)*2 + 1];
            float cc, ss; sincosf(0.5f*th, &ss, &cc);
            float pcv, psv; sincosf(ph, &psv, &pcv);
            g0c[q] = cc; g0r[q] = ss*pcv; g0i[q] = ss*psv;
        }
    }
    __syncthreads();

    v2f a[APT];

    // ---- layer 0 + its ring as a relabel: amp slot k = product state at
    //      n = P(al^k) = nb ^ Pm(k), nb = P(al). Varying bits: 0,1,2 and 10,11.
    {
        const unsigned nb = Pm(al);
        v2f thrP = (v2f){1.f, 0.f};
        #pragma unroll
        for (int bb = 3; bb <= 9; ++bb) {
            const int q = 11 - bb;
            const bool bit = (nb >> bb) & 1u;
            v2f f; f.x = bit ? g0r[q] : g0c[q]; f.y = bit ? g0i[q] : 0.f;
            thrP = cmul(thrP, f);
        }
        const bool n10 = (nb >> 10) & 1u, n11 = (nb >> 11) & 1u;
        v2f f1b; f1b.x = n10 ? g0r[1] : g0c[1]; f1b.y = n10 ? g0i[1] : 0.f;
        v2f f1x; f1x.x = n10 ? g0c[1] : g0r[1]; f1x.y = n10 ? 0.f : g0i[1];
        v2f f0b; f0b.x = n11 ? g0r[0] : g0c[0]; f0b.y = n11 ? g0i[0] : 0.f;
        v2f f0x; f0x.x = n11 ? g0c[0] : g0r[0]; f0x.y = n11 ? 0.f : g0i[0];
        v2f C0 = cmul(thrP, cmul(f1b, f0b));   // k even: bits 10,11 unchanged
        v2f C1 = cmul(thrP, cmul(f1x, f0x));   // k odd: bits 10,11 flipped
        const bool n0 = nb & 1u, n1 = (nb >> 1) & 1u, n2 = (nb >> 2) & 1u;
        v2f fa; fa.x = n0 ? g0r[11] : g0c[11]; fa.y = n0 ? g0i[11] : 0.f;  // f11(nb0)
        v2f fb; fb.x = n0 ? g0c[11] : g0r[11]; fb.y = n0 ? 0.f : g0i[11];  // f11(nb0^1)
        v2f E0 = cmul(C0, fa), E1 = cmul(C0, fb);
        v2f F0 = cmul(C1, fb), F1 = cmul(C1, fa);
        v2f u10; u10.x = n1 ? g0r[10] : g0c[10]; u10.y = n1 ? g0i[10] : 0.f;
        v2f w10; w10.x = n1 ? g0c[10] : g0r[10]; w10.y = n1 ? 0.f : g0i[10];
        v2f u9;  u9.x  = n2 ? g0r[9]  : g0c[9];  u9.y  = n2 ? g0i[9]  : 0.f;
        v2f w9;  w9.x  = n2 ? g0c[9]  : g0r[9];  w9.y  = n2 ? 0.f : g0i[9];
        v2f G0 = cmul(u10, u9), G1 = cmul(w10, u9), G2 = cmul(w10, w9), G3 = cmul(u10, w9);
        a[0] = cmul(E0, G0); a[1] = cmul(F0, G0);
        a[2] = cmul(E1, G1); a[3] = cmul(F1, G1);
        a[4] = cmul(E0, G2); a[5] = cmul(F0, G2);
        a[6] = cmul(E1, G3); a[7] = cmul(F1, G3);
    }

    const float* cs1 = gp;
    const float* cs2 = gp + 24;
    const float* cs3 = gp + 48;
    const v2f thrD1 = *(const v2f*)(gp + 104 + tid*2);
    const v2f thrD2 = *(const v2f*)(gp + 104 + 1024 + tid*2);

    // ================= layer 1 =================
    gates_A(a, cs1, lane);
    {   // A-write, b128 (L1 map keeps k in bits 0..2)
        float4* f4 = (float4*)buf;
        const bool a0 = LA1 & 1u;
        #pragma unroll
        for (int ke = 0; ke < APT; ke += 2) {
            v2f lo = a0 ? a[ke+1] : a[ke];
            v2f hi = a0 ? a[ke]   : a[ke+1];
            f4[(LA1 ^ (unsigned)ke) >> 1] = make_float4(lo.x, lo.y, hi.x, hi.y);
        }
    }
    __syncthreads();
    #pragma unroll
    for (int k = 0; k < APT; ++k) a[k] = buf[LB1 ^ ((unsigned)k << 9)];
    gates_B(a, cs1, lane);
    #pragma unroll
    for (int k = 0; k < APT; ++k) {   // RZ diagonal of layer 1
        v2f kd = *(const v2f*)(gp + 72 + k*2);
        a[k] = cmul(a[k], cmul(thrD1, kd));
    }
    #pragma unroll
    for (int k = 0; k < APT; ++k) buf[LB1 ^ ((unsigned)k << 9)] = a[k];
    __syncthreads();

    // ================= layer 2 (map L∘P) =================
    #pragma unroll
    for (int k = 0; k < APT; ++k) a[k] = buf[LA2 ^ Lm(Pm((unsigned)k))];
    gates_A(a, cs2, lane);
    #pragma unroll
    for (int k = 0; k < APT; ++k) buf[LA2 ^ Lm(Pm((unsigned)k))] = a[k];
    __syncthreads();
    #pragma unroll
    for (int k = 0; k < APT; ++k) a[k] = buf[LB2 ^ Lm(Pm((unsigned)k << 9))];
    gates_B(a, cs2, lane);
    #pragma unroll
    for (int k = 0; k < APT; ++k) {   // RZ diagonal of layer 2
        v2f kd = *(const v2f*)(gp + 72 + 16 + k*2);
        a[k] = cmul(a[k], cmul(thrD2, kd));
    }
    #pragma unroll
    for (int k = 0; k < APT; ++k) buf[LB2 ^ Lm(Pm((unsigned)k << 9))] = a[k];
    __syncthreads();

    // ================= layer 3 (map L∘P², RZ dropped, no B-write) =================
    #pragma unroll
    for (int k = 0; k < APT; ++k) a[k] = buf[LA3 ^ Lm(Pm(Pm((unsigned)k)))];
    gates_A(a, cs3, lane);
    #pragma unroll
    for (int k = 0; k < APT; ++k) buf[LA3 ^ Lm(Pm(Pm((unsigned)k)))] = a[k];
    __syncthreads();
    #pragma unroll
    for (int k = 0; k < APT; ++k) a[k] = buf[LB3 ^ Lm(Pm(Pm((unsigned)k << 9)))];
    gates_B(a, cs3, lane);

    // ---- measurement with final ring as sign-relabel: m = P^{-1}(be ^ k<<9).
    // k-masks collapse to 3 Walsh masks: mu=7 (p<=9), mu=6 (p=10), mu=3 (p=11).
    {
        float p[APT];
        #pragma unroll
        for (int k = 0; k < APT; ++k) p[k] = a[k].x*a[k].x + a[k].y*a[k].y;
        float A = (p[0]-p[1]) - (p[2]-p[3]), B = (p[4]-p[5]) - (p[6]-p[7]);
        float C = (p[0]+p[1]) - (p[2]+p[3]), D = (p[4]+p[5]) - (p[6]+p[7]);
        float w7 = A - B;     // sign (-1)^{k0^k1^k2}
        float w3 = A + B;     // sign (-1)^{k0^k1}
        float w6 = C - D;     // sign (-1)^{k1^k2}
        #pragma unroll
        for (int t = 0; t < 6; ++t) {
            float o7 = __shfl_xor(w7, 1 << t, 64);
            float o6 = __shfl_xor(w6, 1 << t, 64);
            float o3 = __shfl_xor(w3, 1 << t, 64);
            const bool hi = (lane >> t) & 1;
            w7 = hi ? (o7 - w7) : (w7 + o7);
            w6 = hi ? (o6 - w6) : (w6 + o6);
            w3 = hi ? (o3 - w3) : (w3 + o3);
        }
        // lane v holds sum_l (-1)^{<v,l>} ; needed lanes per p (see masks):
        if      (lane == 63) { zred[wv][0] = w7; zred[wv][8] = w3; }
        else if (lane == 47) { zred[wv][1] = w7; }
        else if (lane == 43) { zred[wv][2] = w7; }
        else if (lane == 42) { zred[wv][3] = w7; }
        else if (lane == 10) { zred[wv][4] = w7; }
        else if (lane ==  8) { zred[wv][5] = w7; }
        else if (lane ==  0) { zred[wv][6] = w7; zred[wv][7] = w6; }
    }
    __syncthreads();
    if (tid < NQ) {
        const int p = 11 - tid;                       // qubit tid <-> bit 11-tid
        const int slot = (p == 0) ? 0 : (p <= 4) ? 1 : (p - 3);
        const int wm = (p <= 1 || p == 11) ? 7 : (p == 2) ? 6 : (p == 3) ? 4 : 0;
        float acc = 0.f;
        #pragma unroll
        for (int W = 0; W < 8; ++W) {
            float v = zred[W][slot];
            acc += (__popc(W & wm) & 1) ? -v : v;
        }
        zfin[tid] = acc;
    }
    __syncthreads();

    if (tid < NCLS) {
        float acc = bout[tid];
        #pragma unroll
        for (int q = 0; q < NQ; ++q) acc += zfin[q] * Wout[tid*NQ + q];
        out[b*NCLS + tid] = acc;
    }
}

extern "C" void kernel_launch(void* const* d_in, const int* in_sizes, int n_in,
                              void* d_out, int out_size, void* d_ws, size_t ws_size,
                              hipStream_t stream) {
    const float* x    = (const float*)d_in[0];
    const float* Win  = (const float*)d_in[1];
    const float* bin  = (const float*)d_in[2];
    const float* qw   = (const float*)d_in[3];
    const float* Wout = (const float*)d_in[4];
    const float* bout = (const float*)d_in[5];
    float* gp  = (float*)d_ws;       // 2152 floats
    float* out = (float*)d_out;
    hipLaunchKernelGGL(vqc_setup, dim3(1), dim3(TPB), 0, stream, qw, gp);
    hipLaunchKernelGGL(vqc_kernel, dim3(NBATCH), dim3(TPB), 0, stream,
                       x, Win, bin, qw, Wout, bout, gp, out);
}

// Round 8
// 51.453 us; speedup vs baseline: 1.5618x; 1.0373x over previous
//
#include <hip/hip_runtime.h>
#include <math.h>

#define NQ    12
#define NST   4096
#define NBATCH 2048
#define DIM   64
#define NCLS  4
#define TPB   256
#define APT   16

typedef float v2f __attribute__((ext_vector_type(2)));   // (re, im)

// Ring permutation (round-1 verified): new[d] = old[P(d)]; GF(2)-linear.
constexpr unsigned Pm(unsigned j) { return j ^ (j >> 1) ^ ((j & 1u) * 0xC00u); }
// Storage map: a[0:3] = j[0:3]^j[4:7], a[4:11] = j[4:11]. Involution, bijective.
// All six access patterns (A/B phase x maps S, S∘P, S∘P²) verified rank-4 over
// lane bits -> bank-conflict-free b64.
constexpr unsigned Sm(unsigned j) { return j ^ ((j >> 4) & 0xFu); }

// A-phase lane->logical: l0..l5,w0,w1 -> bits 4..11 ; k -> bits 0..3
__device__ __forceinline__ unsigned alphaA(unsigned t) { return t << 4; }
// B-phase: l2..l5 -> bits 0..3, w0,w1 -> bits 4,5, l0,l1 -> bits 6,7 ; k -> bits 8..11
__device__ __forceinline__ unsigned alphaB(unsigned t) {
    unsigned lane = t & 63u, w = t >> 6;
    return ((lane >> 2) & 0xFu) | (w << 4) | ((lane & 3u) << 6);
}

__device__ __forceinline__ v2f cmul(v2f x, v2f y) {
    v2f r; r.x = x.x*y.x - x.y*y.y; r.y = x.x*y.y + x.y*y.x; return r;
}

// packed f32 ops (VOP3P) — force packing of (re,im) pairs
__device__ __forceinline__ v2f pk_mul(v2f a, v2f b) {
    v2f d; asm("v_pk_mul_f32 %0, %1, %2" : "=v"(d) : "v"(a), "v"(b)); return d;
}
__device__ __forceinline__ v2f pk_fma(v2f a, v2f b, v2f c) {
    v2f d; asm("v_pk_fma_f32 %0, %1, %2, %3" : "=v"(d) : "v"(a), "v"(b), "v"(c)); return d;
}

// lane exchange via quad_perm DPP only (XB in {1,2})
template<int XB>
__device__ __forceinline__ float lx(float v) {
    int i = __float_as_int(v);
    if constexpr (XB == 1)
        return __int_as_float(__builtin_amdgcn_update_dpp(i, i, 0xB1, 0xF, 0xF, true)); // [1,0,3,2]
    else
        return __int_as_float(__builtin_amdgcn_update_dpp(i, i, 0x4E, 0xF, 0xF, true)); // [2,3,0,1]
}

// real RY on intra-register bit P (0..3)
template<int P>
__device__ __forceinline__ void intra_g(v2f (&a)[APT], float c, float s) {
    const v2f cc = {c, c}, ss = {s, s}, ns = {-s, -s};
    #pragma unroll
    for (int k = 0; k < APT; ++k) {
        if (!(k & (1 << P))) {
            const int k1 = k | (1 << P);
            v2f x0 = a[k], x1 = a[k1];
            a[k]  = pk_fma(ns, x1, pk_mul(cc, x0));   // c*x0 - s*x1
            a[k1] = pk_fma(cc, x1, pk_mul(ss, x0));   // s*x0 + c*x1
        }
    }
}

// real RY on lane bit XB (quad_perm exchange)
template<int XB>
__device__ __forceinline__ void lane_g(v2f (&a)[APT], float c, float s, int lane) {
    const float br = (lane & XB) ? s : -s;
    const v2f cc = {c, c}, bb = {br, br};
    #pragma unroll
    for (int k = 0; k < APT; ++k) {
        v2f o; o.x = lx<XB>(a[k].x); o.y = lx<XB>(a[k].y);
        a[k] = pk_fma(bb, o, pk_mul(cc, a[k]));
    }
}

// A phase: intra bits0-3 = q11,q10,q9,q8 ; lanes l0->bit4 (q7), l1->bit5 (q6)
__device__ __forceinline__ void gates_A(v2f (&a)[APT], const float* __restrict__ cs, int lane) {
    intra_g<0>(a, cs[22], cs[23]);
    intra_g<1>(a, cs[20], cs[21]);
    intra_g<2>(a, cs[18], cs[19]);
    intra_g<3>(a, cs[16], cs[17]);
    lane_g<1>(a, cs[14], cs[15], lane);
    lane_g<2>(a, cs[12], cs[13], lane);
}
// B phase: intra k bits -> logical 8-11 = q3,q2,q1,q0 ; l0->bit6 (q5), l1->bit7 (q4)
__device__ __forceinline__ void gates_B(v2f (&a)[APT], const float* __restrict__ cs, int lane) {
    intra_g<0>(a, cs[6], cs[7]);
    intra_g<1>(a, cs[4], cs[5]);
    intra_g<2>(a, cs[2], cs[3]);
    intra_g<3>(a, cs[0], cs[1]);
    lane_g<1>(a, cs[10], cs[11], lane);
    lane_g<2>(a, cs[8],  cs[9],  lane);
}

// ws layout (floats): [0..71] RY c/s layers1-3 (24/layer, q*2);
// [72..135] kD layers1-2 (16 v2f each); [136..1159] thrD layers1-2 (256 v2f each)
__global__ void vqc_setup(const float* __restrict__ qw, float* __restrict__ gp) {
    const int t = threadIdx.x;
    if (t < 36) {
        int l = t / 12 + 1, q = t % 12;
        float cc, ss; sincosf(0.5f * qw[(l*NQ + q)*2], &ss, &cc);
        gp[(l-1)*24 + q*2 + 0] = cc;
        gp[(l-1)*24 + q*2 + 1] = ss;
    }
    if (t < 32) {                       // kD: logical bit 8+i -> qubit 3-i
        int l = t / 16 + 1, k = t % 16;
        float ang = 0.f;
        #pragma unroll
        for (int i = 0; i < 4; ++i)
            if ((k >> i) & 1) ang += qw[(l*NQ + (3 - i))*2 + 1];
        float s_, c_; sincosf(ang, &s_, &c_);
        gp[72 + (l-1)*32 + k*2 + 0] = c_;
        gp[72 + (l-1)*32 + k*2 + 1] = s_;
    }
    const unsigned j = alphaB((unsigned)t);   // bits 0..7
    #pragma unroll
    for (int l = 1; l <= 2; ++l) {
        float ang = 0.f;
        #pragma unroll
        for (int b = 0; b < 8; ++b)
            if ((j >> b) & 1) ang += qw[(l*NQ + (11 - b))*2 + 1];
        float s_, c_; sincosf(ang, &s_, &c_);
        gp[136 + (l-1)*512 + t*2 + 0] = c_;
        gp[136 + (l-1)*512 + t*2 + 1] = s_;
    }
}

__global__ __launch_bounds__(TPB, 4) void vqc_kernel(
    const float* __restrict__ x,
    const float* __restrict__ Win,
    const float* __restrict__ bin,
    const float* __restrict__ qw,
    const float* __restrict__ Wout,
    const float* __restrict__ bout,
    const float* __restrict__ gp,
    float* __restrict__ out)
{
    __shared__ __align__(16) v2f buf[NST];   // 32 KB
    __shared__ float xs[DIM];
    __shared__ float g0c[NQ], g0r[NQ], g0i[NQ];
    __shared__ float zred[4][10];
    __shared__ float zfin[NQ];

    const int tid  = threadIdx.x;
    const int lane = tid & 63;
    const int wv   = tid >> 6;
    const int b    = blockIdx.x;

    const unsigned aA = alphaA((unsigned)tid), aB = alphaB((unsigned)tid);
    const unsigned A1 = Sm(aA),         B1 = Sm(aB);
    const unsigned A2 = Sm(Pm(aA)),     B2 = Sm(Pm(aB));
    const unsigned A3 = Sm(Pm(Pm(aA))), B3 = Sm(Pm(Pm(aB)));

    // ---- stage x ----
    if (tid < DIM) xs[tid] = x[b*DIM + tid];
    __syncthreads();

    // ---- encoding matvec (16 lanes/qubit); layer-0 factors (RY+RZ folded) ----
    if (tid < 192) {
        const int q = tid >> 4, r = tid & 15;
        float acc = xs[r] * Win[q*DIM + r]
                  + xs[r+16] * Win[q*DIM + r + 16]
                  + xs[r+32] * Win[q*DIM + r + 32]
                  + xs[r+48] * Win[q*DIM + r + 48];
        acc += __shfl_xor(acc, 8, 16);
        acc += __shfl_xor(acc, 4, 16);
        acc += __shfl_xor(acc, 2, 16);
        acc += __shfl_xor(acc, 1, 16);
        if (r == 0) {
            acc += bin[q];
            float ang = tanhf(acc) * 3.14159265358979323846f;
            float th  = ang + qw[(0*NQ + q)*2 + 0];
            float ph  = qw[(0*NQ + q)*2 + 1];
            float cc, ss; sincosf(0.5f*th, &ss, &cc);
            float pcv, psv; sincosf(ph, &psv, &pcv);
            g0c[q] = cc; g0r[q] = ss*pcv; g0i[q] = ss*psv;
        }
    }
    __syncthreads();

    v2f a[APT];

    // ---- layer 0 + first ring as relabel: a[k] = prod-state at n = nb ^ Pm(k) ----
    {
        const unsigned nb = Pm(aA);
        v2f thrP = (v2f){1.f, 0.f};
        #pragma unroll
        for (int bb = 4; bb <= 9; ++bb) {
            const int q = 11 - bb;
            const bool bit = (nb >> bb) & 1u;
            v2f f; f.x = bit ? g0r[q] : g0c[q]; f.y = bit ? g0i[q] : 0.f;
            thrP = cmul(thrP, f);
        }
        const bool n10 = (nb >> 10) & 1u, n11 = (nb >> 11) & 1u;
        v2f h10a; h10a.x = n10 ? g0r[1] : g0c[1]; h10a.y = n10 ? g0i[1] : 0.f;
        v2f h10b; h10b.x = n10 ? g0c[1] : g0r[1]; h10b.y = n10 ? 0.f : g0i[1];
        v2f h11a; h11a.x = n11 ? g0r[0] : g0c[0]; h11a.y = n11 ? g0i[0] : 0.f;
        v2f h11b; h11b.x = n11 ? g0c[0] : g0r[0]; h11b.y = n11 ? 0.f : g0i[0];
        v2f TT0 = cmul(thrP, cmul(h10a, h11a));   // k even
        v2f TT1 = cmul(thrP, cmul(h10b, h11b));   // k odd: bits 10,11 flipped
        // low-nibble factors: bit b (0..3) <-> qubit 11-b
        v2f u[4], w[4];
        #pragma unroll
        for (int bb = 0; bb < 4; ++bb) {
            const int q = 11 - bb;
            const bool bit = (nb >> bb) & 1u;
            u[bb].x = bit ? g0r[q] : g0c[q]; u[bb].y = bit ? g0i[q] : 0.f;
            w[bb].x = bit ? g0c[q] : g0r[q]; w[bb].y = bit ? 0.f : g0i[q];
        }
        v2f P01[4], P23[4];
        #pragma unroll
        for (int c = 0; c < 4; ++c) {
            P01[c] = cmul((c & 1) ? w[0] : u[0], (c & 2) ? w[1] : u[1]);
            P23[c] = cmul((c & 1) ? w[2] : u[2], (c & 2) ? w[3] : u[3]);
        }
        #pragma unroll
        for (int k = 0; k < APT; ++k) {
            const unsigned kp = (unsigned)k ^ ((unsigned)k >> 1);
            v2f g = cmul(P01[kp & 3], P23[(kp >> 2) & 3]);
            a[k] = cmul((k & 1) ? TT1 : TT0, g);
        }
    }

    const float* cs1 = gp, *cs2 = gp + 24, *cs3 = gp + 48;
    const v2f tD1 = *(const v2f*)(gp + 136 + tid*2);
    const v2f tD2 = *(const v2f*)(gp + 136 + 512 + tid*2);

    // ================= layer 1 (map S) =================
    gates_A(a, cs1, lane);
    {   // b128 A-write: k offsets = k, pairs adjacent
        float4* f4 = (float4*)buf;
        const int a0 = (int)(A1 & 1u);
        #pragma unroll
        for (int ke = 0; ke < APT; ke += 2) {
            v2f lo = a0 ? a[ke+1] : a[ke];
            v2f hi = a0 ? a[ke]   : a[ke+1];
            f4[(A1 ^ (unsigned)ke) >> 1] = make_float4(lo.x, lo.y, hi.x, hi.y);
        }
    }
    __syncthreads();
    #pragma unroll
    for (int k = 0; k < APT; ++k) a[k] = buf[B1 ^ ((unsigned)k << 8)];
    gates_B(a, cs1, lane);
    #pragma unroll
    for (int k = 0; k < APT; ++k) {   // RZ diagonal layer 1
        v2f kd = *(const v2f*)(gp + 72 + k*2);
        buf[B1 ^ ((unsigned)k << 8)] = cmul(cmul(a[k], tD1), kd);
    }
    __syncthreads();

    // ================= layer 2 (map S∘P) =================
    #pragma unroll
    for (int k = 0; k < APT; ++k) a[k] = buf[A2 ^ Sm(Pm((unsigned)k))];
    gates_A(a, cs2, lane);
    #pragma unroll
    for (int k = 0; k < APT; ++k) buf[A2 ^ Sm(Pm((unsigned)k))] = a[k];
    __syncthreads();
    #pragma unroll
    for (int k = 0; k < APT; ++k) a[k] = buf[B2 ^ Sm(Pm((unsigned)k << 8))];
    gates_B(a, cs2, lane);
    #pragma unroll
    for (int k = 0; k < APT; ++k) {   // RZ diagonal layer 2
        v2f kd = *(const v2f*)(gp + 72 + 32 + k*2);
        buf[B2 ^ Sm(Pm((unsigned)k << 8))] = cmul(cmul(a[k], tD2), kd);
    }
    __syncthreads();

    // ================= layer 3 (map S∘P², RZ dropped, ends in regs) =================
    #pragma unroll
    for (int k = 0; k < APT; ++k) a[k] = buf[A3 ^ Sm(Pm(Pm((unsigned)k)))];
    gates_A(a, cs3, lane);
    #pragma unroll
    for (int k = 0; k < APT; ++k) buf[A3 ^ Sm(Pm(Pm((unsigned)k)))] = a[k];
    __syncthreads();
    #pragma unroll
    for (int k = 0; k < APT; ++k) a[k] = buf[B3 ^ Sm(Pm(Pm((unsigned)k << 8)))];
    gates_B(a, cs3, lane);

    // ---- measurement; final ring via masks mu_p = P^{-T} e_p on m = aB ^ (k<<8).
    // k-masks: p<=8 -> 0xF (WF), p=9 -> 0xE (WE), p=10 -> 0xC (WC), p=11 -> 0x7 (W7)
    {
        float p[APT];
        #pragma unroll
        for (int k = 0; k < APT; ++k) p[k] = fmaf(a[k].x, a[k].x, a[k].y*a[k].y);
        float A_[8], Bm[8];
        #pragma unroll
        for (int j = 0; j < 8; ++j) { A_[j] = p[2*j] + p[2*j+1]; Bm[j] = p[2*j] - p[2*j+1]; }
        float AA[4], AB[4], BB[4];
        #pragma unroll
        for (int i = 0; i < 4; ++i) {
            AA[i] = A_[2*i] + A_[2*i+1];
            AB[i] = A_[2*i] - A_[2*i+1];
            BB[i] = Bm[2*i] - Bm[2*i+1];
        }
        float WF = BB[0] - BB[1] - BB[2] + BB[3];
        float W7 = BB[0] - BB[1] + BB[2] - BB[3];
        float WE = AB[0] - AB[1] - AB[2] + AB[3];
        float WC = AA[0] - AA[1] - AA[2] + AA[3];
        // 6-step lane Walsh butterflies: lane m ends with sum_l X(l)*(-1)^popc(m&l)
        #pragma unroll
        for (int t = 0; t < 6; ++t) {
            float oF = __shfl_xor(WF, 1 << t, 64);
            float o7 = __shfl_xor(W7, 1 << t, 64);
            float oE = __shfl_xor(WE, 1 << t, 64);
            float oC = __shfl_xor(WC, 1 << t, 64);
            const bool hi = (lane >> t) & 1;
            WF = hi ? (oF - WF) : (WF + oF);
            W7 = hi ? (o7 - W7) : (W7 + o7);
            WE = hi ? (oE - WE) : (WE + oE);
            WC = hi ? (oC - WC) : (WC + oC);
        }
        // lane masks (from nu_p mapped through alphaB): p0..8 -> 63,59,51,35,3,3,3,2,0
        if      (lane == 63) { zred[wv][0] = WF; zred[wv][9] = W7; }
        else if (lane == 59) { zred[wv][1] = WF; }
        else if (lane == 51) { zred[wv][2] = WF; }
        else if (lane == 35) { zred[wv][3] = WF; }
        else if (lane ==  3) { zred[wv][4] = WF; }
        else if (lane ==  2) { zred[wv][5] = WF; }
        else if (lane ==  0) { zred[wv][6] = WF; zred[wv][7] = WE; zred[wv][8] = WC; }
    }
    __syncthreads();
    if (tid < NQ) {     // q = tid ; p = 11-q ; wave-sign masks over (w0,w1)
        const int slotT[12] = {9,8,7,6,5,4,4,4,3,2,1,0};
        const int wmT[12]   = {3,0,0,0,0,0,2,3,3,3,3,3};
        const int sl = slotT[tid], wm = wmT[tid];
        float acc = 0.f;
        #pragma unroll
        for (int W = 0; W < 4; ++W) {
            float v = zred[W][sl];
            acc += (__popc(W & wm) & 1) ? -v : v;
        }
        zfin[tid] = acc;
    }
    __syncthreads();

    if (tid < NCLS) {
        float acc = bout[tid];
        #pragma unroll
        for (int q = 0; q < NQ; ++q) acc += zfin[q] * Wout[tid*NQ + q];
        out[b*NCLS + tid] = acc;
    }
}

extern "C" void kernel_launch(void* const* d_in, const int* in_sizes, int n_in,
                              void* d_out, int out_size, void* d_ws, size_t ws_size,
                              hipStream_t stream) {
    const float* x    = (const float*)d_in[0];
    const float* Win  = (const float*)d_in[1];
    const float* bin  = (const float*)d_in[2];
    const float* qw   = (const float*)d_in[3];
    const float* Wout = (const float*)d_in[4];
    const float* bout = (const float*)d_in[5];
    float* gp  = (float*)d_ws;       // 1160 floats
    float* out = (float*)d_out;
    hipLaunchKernelGGL(vqc_setup, dim3(1), dim3(TPB), 0, stream, qw, gp);
    hipLaunchKernelGGL(vqc_kernel, dim3(NBATCH), dim3(TPB), 0, stream,
                       x, Win, bin, qw, Wout, bout, gp, out);
}